// Round 12
// baseline (46.583 us; speedup 1.0000x reference)
//
#include <hip/hip_runtime.h>

// Problem constants (match reference)
constexpr int B = 128, N = 900, C = 91, M = 100;
// ALPHA=0.25, W_CLASS=2 folded analytically:
// ccls = L*(0.5 - s - s^2) - 1.5*s^2*x,  L = log(1+exp(-x)), s = 1/(1+exp(-x))
constexpr float W_BBOX = 5.0f;
constexpr float W_GIOU = 2.0f;

constexpr int NBX  = 15;          // blocks in n per batch
constexpr int ROWS = N / NBX;     // 60 rows per block
constexpr int BLK  = 256;
constexpr int MQ   = M / 4;       // 25 output quads per row
constexpr int NGRP = 10;          // row-groups; 250 active threads
constexpr int KIT  = ROWS / NGRP; // 6 iterations per thread (exact)

typedef float f32x4 __attribute__((ext_vector_type(4)));

// 8 blocks/CU (=32 waves/CU, 8 waves/SIMD) -> compiler caps VGPR at 64.
__global__ __launch_bounds__(BLK, 8) void hungarian_cost_kernel(
    const float* __restrict__ logits,   // [B, N, C]
    const float* __restrict__ pboxes,   // [B, N, 4] cxcywh
    const int*   __restrict__ tlabels,  // [B, M]
    const float* __restrict__ tboxes,   // [B, M, 4] cxcywh
    float* __restrict__ out)            // [B, N, M]
{
    const int b   = blockIdx.y;
    const int n0  = blockIdx.x * ROWS;
    const int tid = threadIdx.x;

    const int mq   = tid % MQ;        // 0..24 (quad of m)
    const int rgrp = tid / MQ;        // 0..10
    if (rgrp >= NGRP) return;         // 6 idle threads; no barriers anywhere

    const float*  lbase = logits + ((size_t)b * N + n0) * C;  // SGPR base
    const float4* pbp   = reinterpret_cast<const float4*>(pboxes) + (size_t)b * N + n0;
    f32x4*        outq  = reinterpret_cast<f32x4*>(out) + ((size_t)b * N + n0) * MQ;

    // ---- Labels -> element offsets within a logits row (4 VGPR) ----
    const int4 l4 = reinterpret_cast<const int4*>(tlabels + (size_t)b * M)[mq];
    int loff[4] = {l4.x, l4.y, l4.z, l4.w};

    // ---- Targets -> registers: xyxy + area only (20 VGPR) ----
    float tx0[4], ty0[4], tx1[4], ty1[4], tar[4];
    {
        const float4* tbp = reinterpret_cast<const float4*>(tboxes) + (size_t)b * M;
        #pragma unroll
        for (int j = 0; j < 4; ++j) {
            const float4 t = tbp[mq * 4 + j];
            tx0[j] = t.x - 0.5f * t.z;  ty0[j] = t.y - 0.5f * t.w;
            tx1[j] = t.x + 0.5f * t.z;  ty1[j] = t.y + 0.5f * t.w;
            tar[j] = (tx1[j] - tx0[j]) * (ty1[j] - ty0[j]);
        }
    }

    // ---- Depth-2 software pipeline: prologue loads for k=0 ----
    float4 pA, pB;
    float  xA[4], xB[4];
    {
        const float* lr = lbase + rgrp * C;     // uniform-per-wavegroup base
        pA = pbp[rgrp];
        #pragma unroll
        for (int j = 0; j < 4; ++j) xA[j] = lr[loff[j]];
    }

    #pragma unroll
    for (int k = 0; k < KIT; ++k) {
        const int row = rgrp + NGRP * k;

        // ---- Issue k+1's loads BEFORE computing k ----
        if (k + 1 < KIT) {
            const int rown = row + NGRP;
            pB = pbp[rown];
            const float* lr = lbase + rown * C;
            #pragma unroll
            for (int j = 0; j < 4; ++j) xB[j] = lr[loff[j]];
        }
        __builtin_amdgcn_sched_barrier(0);   // loads above, compute below

        const float px0 = pA.x - 0.5f * pA.z, py0 = pA.y - 0.5f * pA.w;
        const float px1 = pA.x + 0.5f * pA.z, py1 = pA.y + 0.5f * pA.w;
        const float parea = (px1 - px0) * (py1 - py0);

        f32x4 res;
        #pragma unroll
        for (int j = 0; j < 4; ++j) {
            // focal class cost (ALPHA/W_CLASS folded):
            // e = exp(-x); L = log(1+e); s = rcp(1+e)
            // ccls = L*(0.5 - s - s^2) - 1.5*s^2*x
            const float x    = xA[j];
            const float e    = __expf(-x);
            const float onep = 1.0f + e;
            const float s    = __builtin_amdgcn_rcpf(onep);
            const float L    = __logf(onep);
            const float s2   = s * s;
            const float ccls = L * ((0.5f - s) - s2) - 1.5f * s2 * x;

            // L1 via xyxy deltas (W_BBOX folded into 2.5/5 weights):
            const float dx0 = px0 - tx0[j], dx1 = px1 - tx1[j];
            const float dy0 = py0 - ty0[j], dy1 = py1 - ty1[j];
            const float l1a = fabsf(dx0 + dx1) + fabsf(dy0 + dy1);
            const float l1b = fabsf(dx1 - dx0) + fabsf(dy1 - dy0);

            // GIoU, single reciprocal:
            // giou = (inter*earea - uni*(earea-uni)) / (uni*earea)
            const float iw = fmaxf(fminf(px1, tx1[j]) - fmaxf(px0, tx0[j]), 0.0f);
            const float ih = fmaxf(fminf(py1, ty1[j]) - fmaxf(py0, ty0[j]), 0.0f);
            const float inter = iw * ih;
            const float uni   = parea + tar[j] - inter;

            const float ew = fmaxf(px1, tx1[j]) - fminf(px0, tx0[j]);
            const float eh = fmaxf(py1, ty1[j]) - fminf(py0, ty0[j]);
            const float earea = ew * eh;

            const float num  = inter * earea - uni * (earea - uni);
            const float rcpD = __builtin_amdgcn_rcpf(uni * earea);

            res[j] = ccls + 2.5f * l1a + 5.0f * l1b - W_GIOU * (num * rcpD);
        }

        // Non-temporal store: no write-allocate RFO on out lines
        __builtin_nontemporal_store(res, &outq[(size_t)row * MQ + mq]);

        // rotate pipeline regs (renames under full unroll)
        pA = pB;
        #pragma unroll
        for (int j = 0; j < 4; ++j) xA[j] = xB[j];
    }
}

extern "C" void kernel_launch(void* const* d_in, const int* in_sizes, int n_in,
                              void* d_out, int out_size, void* d_ws, size_t ws_size,
                              hipStream_t stream) {
    const float* logits  = (const float*)d_in[0];
    const float* pboxes  = (const float*)d_in[1];
    const int*   tlabels = (const int*)d_in[2];
    const float* tboxes  = (const float*)d_in[3];
    float* out = (float*)d_out;

    dim3 grid(NBX, B);
    dim3 block(BLK);
    hipLaunchKernelGGL(hungarian_cost_kernel, grid, block, 0, stream,
                       logits, pboxes, tlabels, tboxes, out);
}

// Round 13
// 27.256 us; speedup vs baseline: 1.7091x; 1.7091x over previous
//
#include <hip/hip_runtime.h>

// Problem constants (match reference)
constexpr int B = 128, N = 900, C = 91, M = 100;
// ALPHA=0.25, W_CLASS=2 folded analytically:
// ccls = L*(0.5 - s - s^2) - 1.5*s^2*x,  L = log(1+exp(-x)), s = 1/(1+exp(-x))
constexpr float W_GIOU = 2.0f;

constexpr int NBX  = 15;          // blocks in n per batch
constexpr int ROWS = N / NBX;     // 60 rows per block
constexpr int BLK  = 256;
constexpr int MQ   = M / 4;       // 25 output quads per row
constexpr int NGRP = 10;          // row-groups; 250 active threads
constexpr int KIT  = ROWS / NGRP; // 6 iterations per thread (exact)

typedef float f32x2 __attribute__((ext_vector_type(2)));
typedef float f32x4 __attribute__((ext_vector_type(4)));

__global__ __launch_bounds__(BLK) void hungarian_cost_kernel(
    const float* __restrict__ logits,   // [B, N, C]
    const float* __restrict__ pboxes,   // [B, N, 4] cxcywh
    const int*   __restrict__ tlabels,  // [B, M]
    const float* __restrict__ tboxes,   // [B, M, 4] cxcywh
    float* __restrict__ out)            // [B, N, M]
{
    const int b   = blockIdx.y;
    const int n0  = blockIdx.x * ROWS;
    const int tid = threadIdx.x;

    const int mq   = tid % MQ;        // 0..24 (quad of m)
    const int rgrp = tid / MQ;        // 0..10
    if (rgrp >= NGRP) return;         // 6 idle threads; no barriers anywhere

    const float*  lbase = logits + ((size_t)b * N + n0) * C;
    const float4* pbp   = reinterpret_cast<const float4*>(pboxes) + (size_t)b * N + n0;
    f32x4*        outq  = reinterpret_cast<f32x4*>(out) + ((size_t)b * N + n0) * MQ;

    // ---- Labels (gather addresses depend on them) ----
    const int4 l4 = reinterpret_cast<const int4*>(tlabels + (size_t)b * M)[mq];
    const int labj[4] = {l4.x, l4.y, l4.z, l4.w};

    // ---- Targets -> registers as (x,y) pairs: T0=(x0,y0), T1=(x1,y1), area ----
    f32x2 T0[4], T1[4];
    float tar[4];
    {
        const float4* tbp = reinterpret_cast<const float4*>(tboxes) + (size_t)b * M;
        #pragma unroll
        for (int j = 0; j < 4; ++j) {
            const float4 t = tbp[mq * 4 + j];
            const f32x2 c = {t.x, t.y};
            const f32x2 h = {0.5f * t.z, 0.5f * t.w};
            T0[j] = c - h;
            T1[j] = c + h;
            tar[j] = (T1[j].x - T0[j].x) * (T1[j].y - T0[j].y);
        }
    }

    // ---- Depth-2 software pipeline: prologue loads for k=0 ----
    float4 pA, pB;
    float  xA[4], xB[4];
    {
        pA = pbp[rgrp];
        const float* lr = lbase + rgrp * C;
        #pragma unroll
        for (int j = 0; j < 4; ++j) xA[j] = lr[labj[j]];
    }

    #pragma unroll
    for (int k = 0; k < KIT; ++k) {
        const int row = rgrp + NGRP * k;

        // ---- Issue k+1's loads BEFORE computing k ----
        if (k + 1 < KIT) {
            const int rown = row + NGRP;
            pB = pbp[rown];
            const float* lr = lbase + rown * C;
            #pragma unroll
            for (int j = 0; j < 4; ++j) xB[j] = lr[labj[j]];
        }
        __builtin_amdgcn_sched_barrier(0);   // loads above, compute below

        // pred box as packed (x,y) pairs
        const f32x2 Pc = {pA.x, pA.y};
        const f32x2 Ph = {0.5f * pA.z, 0.5f * pA.w};
        const f32x2 P0 = Pc - Ph;
        const f32x2 P1 = Pc + Ph;
        const float parea = (P1.x - P0.x) * (P1.y - P0.y);
        const f32x2 zero = {0.0f, 0.0f};

        f32x4 res;
        #pragma unroll
        for (int j = 0; j < 4; ++j) {
            // focal class cost (ALPHA/W_CLASS folded):
            // e = exp(-x); L = log(1+e); s = rcp(1+e)
            // ccls = L*(0.5 - s - s^2) - 1.5*s^2*x
            const float x    = xA[j];
            const float e    = __expf(-x);
            const float onep = 1.0f + e;
            const float s    = __builtin_amdgcn_rcpf(onep);
            const float L    = __logf(onep);
            const float s2   = s * s;
            const float ccls = L * ((0.5f - s) - s2) - 1.5f * s2 * x;

            // L1 via packed xyxy deltas:
            // l1 = 2.5*(|dx0+dx1|+|dy0+dy1|) + 5*(|dx1-dx0|+|dy1-dy0|)
            const f32x2 d0 = P0 - T0[j];
            const f32x2 d1 = P1 - T1[j];
            const f32x2 va = __builtin_elementwise_abs(d0 + d1);
            const f32x2 vb = __builtin_elementwise_abs(d1 - d0);
            const float l1w = 2.5f * (va.x + va.y) + 5.0f * (vb.x + vb.y);

            // GIoU with packed min/max, single reciprocal:
            const f32x2 iwh = __builtin_elementwise_max(
                __builtin_elementwise_min(P1, T1[j]) -
                __builtin_elementwise_max(P0, T0[j]), zero);
            const float inter = iwh.x * iwh.y;

            const f32x2 ewh = __builtin_elementwise_max(P1, T1[j]) -
                              __builtin_elementwise_min(P0, T0[j]);
            const float earea = ewh.x * ewh.y;

            const float uni  = parea + tar[j] - inter;
            const float num  = inter * earea - uni * (earea - uni);
            const float rcpD = __builtin_amdgcn_rcpf(uni * earea);

            res[j] = ccls + l1w - W_GIOU * (num * rcpD);
        }

        // Non-temporal store: no write-allocate RFO on out lines
        __builtin_nontemporal_store(res, &outq[(size_t)row * MQ + mq]);

        // rotate pipeline regs (renames under full unroll)
        pA = pB;
        #pragma unroll
        for (int j = 0; j < 4; ++j) xA[j] = xB[j];
    }
}

extern "C" void kernel_launch(void* const* d_in, const int* in_sizes, int n_in,
                              void* d_out, int out_size, void* d_ws, size_t ws_size,
                              hipStream_t stream) {
    const float* logits  = (const float*)d_in[0];
    const float* pboxes  = (const float*)d_in[1];
    const int*   tlabels = (const int*)d_in[2];
    const float* tboxes  = (const float*)d_in[3];
    float* out = (float*)d_out;

    dim3 grid(NBX, B);
    dim3 block(BLK);
    hipLaunchKernelGGL(hungarian_cost_kernel, grid, block, 0, stream,
                       logits, pboxes, tlabels, tboxes, out);
}

// Round 14
// 27.084 us; speedup vs baseline: 1.7200x; 1.0064x over previous
//
#include <hip/hip_runtime.h>

// Problem constants (match reference)
constexpr int B = 128, N = 900, C = 91, M = 100;
// ALPHA=0.25, W_CLASS=2 folded analytically:
// ccls = L*(0.5 - s - s^2) - 1.5*s^2*x,  L = log(1+exp(-x)), s = 1/(1+exp(-x))
constexpr float W_GIOU = 2.0f;

constexpr int NBX  = 15;          // blocks in n per batch
constexpr int ROWS = N / NBX;     // 60 rows per block
constexpr int BLK  = 256;
constexpr int MH   = M / 2;       // 50 output pairs per row
constexpr int NGRP = BLK / MH;    // 5 row-groups; 250 active threads
constexpr int KIT  = ROWS / NGRP; // 12 iterations per thread (exact)

typedef float f32x2 __attribute__((ext_vector_type(2)));

__global__ __launch_bounds__(BLK) void hungarian_cost_kernel(
    const float* __restrict__ logits,   // [B, N, C]
    const float* __restrict__ pboxes,   // [B, N, 4] cxcywh
    const int*   __restrict__ tlabels,  // [B, M]
    const float* __restrict__ tboxes,   // [B, M, 4] cxcywh
    float* __restrict__ out)            // [B, N, M]
{
    const int b   = blockIdx.y;
    const int n0  = blockIdx.x * ROWS;
    const int tid = threadIdx.x;

    const int mh   = tid % MH;        // 0..49 (pair of m)
    const int rgrp = tid / MH;        // 0..5
    if (rgrp >= NGRP) return;         // 6 idle threads; no barriers anywhere

    const float*  lbase = logits + ((size_t)b * N + n0) * C;
    const float4* pbp   = reinterpret_cast<const float4*>(pboxes) + (size_t)b * N + n0;
    f32x2*        outh  = reinterpret_cast<f32x2*>(out) + ((size_t)b * N + n0) * MH;

    // ---- Labels (2 per thread) ----
    const int2 l2 = reinterpret_cast<const int2*>(tlabels + (size_t)b * M)[mh];
    const int labj[2] = {l2.x, l2.y};

    // ---- Targets -> registers as (x,y) pairs: 10 VGPR total ----
    f32x2 T0[2], T1[2];
    float tar[2];
    {
        const float4* tbp = reinterpret_cast<const float4*>(tboxes) + (size_t)b * M;
        #pragma unroll
        for (int j = 0; j < 2; ++j) {
            const float4 t = tbp[mh * 2 + j];
            const f32x2 c = {t.x, t.y};
            const f32x2 h = {0.5f * t.z, 0.5f * t.w};
            T0[j] = c - h;
            T1[j] = c + h;
            tar[j] = (T1[j].x - T0[j].x) * (T1[j].y - T0[j].y);
        }
    }

    // ---- Depth-2 software pipeline: prologue loads for k=0 ----
    float4 pA, pB;
    float  xA[2], xB[2];
    {
        pA = pbp[rgrp];
        const float* lr = lbase + rgrp * C;
        #pragma unroll
        for (int j = 0; j < 2; ++j) xA[j] = lr[labj[j]];
    }

    #pragma unroll
    for (int k = 0; k < KIT; ++k) {
        const int row = rgrp + NGRP * k;

        // ---- Issue k+1's loads BEFORE computing k ----
        if (k + 1 < KIT) {
            const int rown = row + NGRP;
            pB = pbp[rown];
            const float* lr = lbase + rown * C;
            #pragma unroll
            for (int j = 0; j < 2; ++j) xB[j] = lr[labj[j]];
        }
        __builtin_amdgcn_sched_barrier(0);   // loads above, compute below

        // pred box as packed (x,y) pairs
        const f32x2 Pc = {pA.x, pA.y};
        const f32x2 Ph = {0.5f * pA.z, 0.5f * pA.w};
        const f32x2 P0 = Pc - Ph;
        const f32x2 P1 = Pc + Ph;
        const float parea = (P1.x - P0.x) * (P1.y - P0.y);
        const f32x2 zero = {0.0f, 0.0f};

        f32x2 res;
        #pragma unroll
        for (int j = 0; j < 2; ++j) {
            // focal class cost (ALPHA/W_CLASS folded):
            // e = exp(-x); L = log(1+e); s = rcp(1+e)
            // ccls = L*(0.5 - s - s^2) - 1.5*s^2*x
            const float x    = xA[j];
            const float e    = __expf(-x);
            const float onep = 1.0f + e;
            const float s    = __builtin_amdgcn_rcpf(onep);
            const float L    = __logf(onep);
            const float s2   = s * s;
            const float ccls = L * ((0.5f - s) - s2) - 1.5f * s2 * x;

            // L1 via packed xyxy deltas:
            // l1 = 2.5*(|dx0+dx1|+|dy0+dy1|) + 5*(|dx1-dx0|+|dy1-dy0|)
            const f32x2 d0 = P0 - T0[j];
            const f32x2 d1 = P1 - T1[j];
            const f32x2 va = __builtin_elementwise_abs(d0 + d1);
            const f32x2 vb = __builtin_elementwise_abs(d1 - d0);
            const float l1w = 2.5f * (va.x + va.y) + 5.0f * (vb.x + vb.y);

            // GIoU with packed min/max, single reciprocal:
            const f32x2 iwh = __builtin_elementwise_max(
                __builtin_elementwise_min(P1, T1[j]) -
                __builtin_elementwise_max(P0, T0[j]), zero);
            const float inter = iwh.x * iwh.y;

            const f32x2 ewh = __builtin_elementwise_max(P1, T1[j]) -
                              __builtin_elementwise_min(P0, T0[j]);
            const float earea = ewh.x * ewh.y;

            const float uni  = parea + tar[j] - inter;
            const float num  = inter * earea - uni * (earea - uni);
            const float rcpD = __builtin_amdgcn_rcpf(uni * earea);

            res[j] = ccls + l1w - W_GIOU * (num * rcpD);
        }

        // Non-temporal float2 store: linear in tid (perfectly coalesced)
        __builtin_nontemporal_store(res, &outh[(size_t)row * MH + mh]);

        // rotate pipeline regs (renames under full unroll)
        pA = pB;
        xA[0] = xB[0];
        xA[1] = xB[1];
    }
}

extern "C" void kernel_launch(void* const* d_in, const int* in_sizes, int n_in,
                              void* d_out, int out_size, void* d_ws, size_t ws_size,
                              hipStream_t stream) {
    const float* logits  = (const float*)d_in[0];
    const float* pboxes  = (const float*)d_in[1];
    const int*   tlabels = (const int*)d_in[2];
    const float* tboxes  = (const float*)d_in[3];
    float* out = (float*)d_out;

    dim3 grid(NBX, B);
    dim3 block(BLK);
    hipLaunchKernelGGL(hungarian_cost_kernel, grid, block, 0, stream,
                       logits, pboxes, tlabels, tboxes, out);
}